// Round 3
// baseline (265.211 us; speedup 1.0000x reference)
//
#include <hip/hip_runtime.h>

// MHA: B=2, S=2048, D=1024, H=16, HD=64. fp32 in/out, bf16 MFMA internally.
// ws layout (64 MB): qb/kb/vb bf16 [4096,1024] @0/8/16MB; Wq/k/v/o^T bf16
// [1024,1024] @24/26/28/30MB; q(pre-scaled 0.125*log2e),k [B,H,S,HD] @32/40MB;
// v^T [B,H,HD,S] @48MB; bmw u32 mask-words [64][32][32][2][16] @56MB (8MB);
// ctx bf16 @16MB (aliases vb).
//
// R12: flash was latency-bound at 2 waves/SIMD (MfmaUtil 29, VALU 29, occ 21%;
// wave count structurally capped at 2048 by 32-qrows/wave). Key-split 2-way:
// each block = 64 q-rows, wave pairs share 32 q-rows / disjoint key halves,
// (O,l) combined once at end via LDS (intra-block, no atomics). 4096 waves,
// single-buffered K/V per half (36.8KB LDS, 4 blocks/CU), reg-staged 2-deep
// prefetch, launch_bounds(256,3) -> 12+ waves/CU. Total MFMA/VALU/LDS work
// unchanged -- pure occupancy increase.

using s8v = __attribute__((ext_vector_type(8))) short;   // 8 bf16 (4 VGPRs)
using f4v = __attribute__((ext_vector_type(4))) float;   // MFMA acc (16x16)
using f16v = __attribute__((ext_vector_type(16))) float; // MFMA acc (32x32)
typedef unsigned long long u64;

__device__ __forceinline__ unsigned short f2bf(float f) {
  union { float f; unsigned int u; } v; v.f = f;
  return (unsigned short)((v.u + 0x7fffu + ((v.u >> 16) & 1u)) >> 16);  // RNE
}

// pack two f32 -> two bf16 (truncation): lo | hi<<16
__device__ __forceinline__ unsigned pkbf(float lo, float hi2) {
  return __builtin_amdgcn_perm(__float_as_uint(hi2), __float_as_uint(lo), 0x07060302);
}

__device__ __forceinline__ void gll16(const void* g, void* l) {
  __builtin_amdgcn_global_load_lds(
      (const __attribute__((address_space(1))) unsigned int*)g,
      (__attribute__((address_space(3))) unsigned int*)l, 16, 0, 0);
}

// ---------- merged prep: f2b (QKV), wtrans (4 weights), packed mask words ----------
// mask words: for flash lane (l31,hi) at (rowblk,it): 16 u32, widx = ni*8+kcl*4+e,
// word = (mask[q][k0]?0xFFFF:0) | (mask[q][k0+1]?0xFFFF0000:0),
// k0 = 64*it + 32*ni + 16*kcl + 4*hi + (e>>1)*8 + (e&1)*2, q = rowblk*32+l31.
__global__ void prep_kernel(const float* __restrict__ Q, const float* __restrict__ K,
                            const float* __restrict__ V,
                            unsigned short* __restrict__ qb, unsigned short* __restrict__ kb,
                            unsigned short* __restrict__ vb,
                            const float* __restrict__ W0, const float* __restrict__ W1,
                            const float* __restrict__ W2, const float* __restrict__ W3,
                            unsigned short* __restrict__ T0, unsigned short* __restrict__ T1,
                            unsigned short* __restrict__ T2, unsigned short* __restrict__ T3,
                            const int* __restrict__ mask, unsigned* __restrict__ bmw) {
  __shared__ unsigned short t[64][72];
  const int bid = blockIdx.x, tid = threadIdx.x;
  if (bid < 12288) {
    int z = bid >> 12;
    int idx = (bid & 4095) * 256 + tid;
    const float* in = (z == 0) ? Q : (z == 1) ? K : V;
    unsigned short* out = (z == 0) ? qb : (z == 1) ? kb : vb;
    float4 v = ((const float4*)in)[idx];
    ushort4 o;
    o.x = f2bf(v.x); o.y = f2bf(v.y); o.z = f2bf(v.z); o.w = f2bf(v.w);
    ((ushort4*)out)[idx] = o;
  } else if (bid < 13312) {
    int b = bid - 12288;
    int z = b >> 8, rem = b & 255;
    int k0 = (rem >> 4) * 64, n0 = (rem & 15) * 64;
    const float* W = (z == 0) ? W0 : (z == 1) ? W1 : (z == 2) ? W2 : W3;
    unsigned short* Wt = (z == 0) ? T0 : (z == 1) ? T1 : (z == 2) ? T2 : T3;
    for (int p = 0; p < 4; ++p) {
      int idx = p * 256 + tid;
      int row = idx >> 4, c4 = idx & 15;
      float4 v = *(const float4*)&W[(size_t)(k0 + row) * 1024 + n0 + c4 * 4];
      t[row][c4 * 4 + 0] = f2bf(v.x);
      t[row][c4 * 4 + 1] = f2bf(v.y);
      t[row][c4 * 4 + 2] = f2bf(v.z);
      t[row][c4 * 4 + 3] = f2bf(v.w);
    }
    __syncthreads();
    for (int p = 0; p < 2; ++p) {
      int idx = p * 256 + tid;
      int j = idx >> 3, c8 = idx & 7;
      unsigned short tmp[8];
      for (int i = 0; i < 8; ++i) tmp[i] = t[c8 * 8 + i][j];
      uint4 o;
      o.x = tmp[0] | ((unsigned)tmp[1] << 16);
      o.y = tmp[2] | ((unsigned)tmp[3] << 16);
      o.z = tmp[4] | ((unsigned)tmp[5] << 16);
      o.w = tmp[6] | ((unsigned)tmp[7] << 16);
      *(uint4*)&Wt[(size_t)(n0 + j) * 1024 + k0 + c8 * 8] = o;
    }
  } else {
    int g = (bid - 13312) * 256 + tid;          // [0, 2^21)
    int widx = g & 15, hi = (g >> 4) & 1, l31 = (g >> 5) & 31;
    int it = (g >> 10) & 31, rowblk = g >> 15;
    int ni = widx >> 3, kcl = (widx >> 2) & 1, e = widx & 3;
    int kk = 64 * it + 32 * ni + 16 * kcl + 4 * hi + (e >> 1) * 8 + (e & 1) * 2;
    int qrow = rowblk * 32 + l31;
    const int* mrow = mask + (size_t)qrow * 2048 + kk;
    unsigned wd = (mrow[0] ? 0xFFFFu : 0u) | (mrow[1] ? 0xFFFF0000u : 0u);
    bmw[g] = wd;
  }
}

// ---------- fused QKV projection GEMM, 64x128 tile (R6 config) ----------
// z=0: q*(0.125*log2e) -> [B,H,S,HD]; z=1: k -> [B,H,S,HD]; z=2: v -> v^T [B,H,HD,S]
__global__ __launch_bounds__(256) void proj3_kernel(
    const unsigned short* __restrict__ A0, const unsigned short* __restrict__ A1,
    const unsigned short* __restrict__ A2,
    const unsigned short* __restrict__ W0, const unsigned short* __restrict__ W1,
    const unsigned short* __restrict__ W2,
    const float* __restrict__ b0, const float* __restrict__ b1, const float* __restrict__ b2,
    unsigned short* __restrict__ oq, unsigned short* __restrict__ ok,
    unsigned short* __restrict__ ovt) {
  const int z = blockIdx.z;
  const unsigned short* A  = (z == 0) ? A0 : (z == 1) ? A1 : A2;
  const unsigned short* Wt = (z == 0) ? W0 : (z == 1) ? W1 : W2;
  const float* bias        = (z == 0) ? b0 : (z == 1) ? b1 : b2;

  __shared__ __align__(16) unsigned short As[64 * 32];
  __shared__ __align__(16) unsigned short Bs[128 * 32];

  const int tid = threadIdx.x;
  const int lane = tid & 63, w = tid >> 6, ln = lane & 15, quad = lane >> 4;
  const int wm = (w & 1) * 32, wn = (w >> 1) * 64;
  const int m0 = blockIdx.x * 64, n0 = blockIdx.y * 128;

  const int slr = lane >> 2;
  const int schunk = (lane & 3) ^ ((lane >> 3) & 3);
  const int cfrag = (quad ^ ((ln >> 1) & 3)) * 8;

  f4v zero = {0.f, 0.f, 0.f, 0.f};
  f4v acc[2][4];
  for (int mi = 0; mi < 2; ++mi)
    for (int ni = 0; ni < 4; ++ni) acc[mi][ni] = zero;

  for (int kt = 0; kt < 1024; kt += 32) {
    __syncthreads();
    gll16(&A[(size_t)(m0 + w * 16 + slr) * 1024 + kt + schunk * 8],        &As[(w * 16) * 32]);
    gll16(&Wt[(size_t)(n0 + w * 32 + slr) * 1024 + kt + schunk * 8],       &Bs[(w * 32) * 32]);
    gll16(&Wt[(size_t)(n0 + w * 32 + 16 + slr) * 1024 + kt + schunk * 8],  &Bs[(w * 32 + 16) * 32]);
    __syncthreads();
    s8v a[2], b[4];
    for (int mi = 0; mi < 2; ++mi) a[mi] = *(const s8v*)&As[(wm + mi * 16 + ln) * 32 + cfrag];
    for (int ni = 0; ni < 4; ++ni) b[ni] = *(const s8v*)&Bs[(wn + ni * 16 + ln) * 32 + cfrag];
    if (z < 2) {
      for (int mi = 0; mi < 2; ++mi)
        for (int ni = 0; ni < 4; ++ni)
          acc[mi][ni] = __builtin_amdgcn_mfma_f32_16x16x32_bf16(a[mi], b[ni], acc[mi][ni], 0, 0, 0);
    } else {
      for (int mi = 0; mi < 2; ++mi)
        for (int ni = 0; ni < 4; ++ni)
          acc[mi][ni] = __builtin_amdgcn_mfma_f32_16x16x32_bf16(b[ni], a[mi], acc[mi][ni], 0, 0, 0);
    }
  }

  if (z < 2) {
    const float qscale = (z == 0) ? 0.18033688f : 1.0f;  // 0.125 * log2(e)
    unsigned short* outp = (z == 0) ? oq : ok;
    for (int mi = 0; mi < 2; ++mi) {
      int rb = m0 + wm + mi * 16 + quad * 4;
      int b_ = rb >> 11;
      for (int ni = 0; ni < 4; ++ni) {
        int col = n0 + wn + ni * 16 + ln;
        float bvv = bias[col];
        int h = col >> 6, hd = col & 63;
        size_t ob = (size_t)(b_ * 16 + h) * 2048;
        for (int r = 0; r < 4; ++r) {
          int s = (rb + r) & 2047;
          outp[(ob + s) * 64 + hd] = f2bf((acc[mi][ni][r] + bvv) * qscale);
        }
      }
    }
  } else {
    for (int ni = 0; ni < 4; ++ni) {
      for (int r = 0; r < 4; ++r) {
        int colw = n0 + wn + ni * 16 + quad * 4 + r;
        int h = colw >> 6, hd = colw & 63;
        float bvv = bias[colw];
        for (int mi = 0; mi < 2; ++mi) {
          int sg = m0 + wm + mi * 16 + ln;
          int b_ = sg >> 11, ss = sg & 2047;
          ovt[((size_t)(b_ * 16 + h) * 64 + hd) * 2048 + ss] = f2bf(acc[mi][ni][r] + bvv);
        }
      }
    }
  }
}

// ---------- flash attention R12: 256 thr, 4 waves = 2 qgroups x 2 key-halves ----------
__global__ __launch_bounds__(256, 3) void flash_kernel(
    const unsigned short* __restrict__ q, const unsigned short* __restrict__ k,
    const unsigned short* __restrict__ vt, const unsigned* __restrict__ bmw,
    unsigned short* __restrict__ ctx) {
  __shared__ __align__(16) unsigned short k_s[2][64][72];  // [half][key][hd]
  __shared__ __align__(16) unsigned short v_s[2][64][72];  // [half][hd][key]

  const int tid = threadIdx.x;
  const int lane = tid & 63, w = tid >> 6;
  const int l31 = lane & 31, hi = lane >> 5;
  const int h = w & 1;    // key half (0: keys 0..1023, 1: keys 1024..2047)
  const int g = w >> 1;   // q row-group (32 rows) within block
  const int q0 = blockIdx.x * 64;
  const int bh = blockIdx.y;
  const unsigned short* qg  = q  + ((size_t)bh * 2048 + q0) * 64;
  const unsigned short* kgb = k  + (size_t)bh * 2048 * 64;
  const unsigned short* vgb = vt + (size_t)bh * 64 * 2048;
  // mask words [rowblk][it][l31][hi][16]; this wave: rowblk=bx*2+g, it=h*16+i
  const unsigned* mwp = bmw + ((size_t)(blockIdx.x * 2 + g) * 32 + h * 16) * 1024
                        + l31 * 32 + hi * 16;

  // Q fragments direct from global
  const int qrow = g * 32 + l31;
  s8v qf[4];
#pragma unroll
  for (int c = 0; c < 4; ++c)
    qf[c] = *(const s8v*)&qg[(size_t)qrow * 64 + c * 16 + hi * 8];

  s8v ones;
#pragma unroll
  for (int i = 0; i < 8; ++i) ones[i] = (short)0x3F80;
  f16v zf;
#pragma unroll
  for (int i = 0; i < 16; ++i) zf[i] = 0.f;

  // staging: all 256 threads stage all 4 tiles (K_A,K_B,V_A,V_B), 8 uint4/thread
  const int srow = tid >> 3, sc8 = tid & 7;  // rows srow and srow+32

  uint4 ka0, ka1, kb0, kb1, va0, va1, vb0, vb1;
  auto LOADT = [&](int it) {
    const int kA = it * 64, kB = 1024 + it * 64;
    ka0 = *(const uint4*)&kgb[(size_t)(kA + srow) * 64 + sc8 * 8];
    ka1 = *(const uint4*)&kgb[(size_t)(kA + srow + 32) * 64 + sc8 * 8];
    kb0 = *(const uint4*)&kgb[(size_t)(kB + srow) * 64 + sc8 * 8];
    kb1 = *(const uint4*)&kgb[(size_t)(kB + srow + 32) * 64 + sc8 * 8];
    va0 = *(const uint4*)&vgb[(size_t)srow * 2048 + kA + sc8 * 8];
    va1 = *(const uint4*)&vgb[(size_t)(srow + 32) * 2048 + kA + sc8 * 8];
    vb0 = *(const uint4*)&vgb[(size_t)srow * 2048 + kB + sc8 * 8];
    vb1 = *(const uint4*)&vgb[(size_t)(srow + 32) * 2048 + kB + sc8 * 8];
  };
  auto WRITET = [&]() {
    *(uint4*)&k_s[0][srow][sc8 * 8] = ka0;
    *(uint4*)&k_s[0][srow + 32][sc8 * 8] = ka1;
    *(uint4*)&k_s[1][srow][sc8 * 8] = kb0;
    *(uint4*)&k_s[1][srow + 32][sc8 * 8] = kb1;
    *(uint4*)&v_s[0][srow][sc8 * 8] = va0;
    *(uint4*)&v_s[0][srow + 32][sc8 * 8] = va1;
    *(uint4*)&v_s[1][srow][sc8 * 8] = vb0;
    *(uint4*)&v_s[1][srow + 32][sc8 * 8] = vb1;
  };

  LOADT(0);
  WRITET();
  LOADT(1);
  __syncthreads();

  f16v o0, o1, lac;
#pragma unroll
  for (int i = 0; i < 16; ++i) { o0[i] = 0.f; o1[i] = 0.f; lac[i] = 0.f; }

  for (int i = 0; i < 16; ++i) {
    // prefetch mask words (L2-resident; used after the S chain)
    const uint4* mw4 = (const uint4*)(mwp + i * 1024);
    const uint4 mwA = mw4[0], mwB = mw4[1], mwC = mw4[2], mwD = mw4[3];

    // S^T = K.Q^T over HD=64 (zero-C first chunk)
    __builtin_amdgcn_s_setprio(1);
    s8v ak0 = *(const s8v*)&k_s[h][l31][hi * 8];
    s8v ak1 = *(const s8v*)&k_s[h][32 + l31][hi * 8];
    f16v s0 = __builtin_amdgcn_mfma_f32_32x32x16_bf16(ak0, qf[0], zf, 0, 0, 0);
    f16v s1 = __builtin_amdgcn_mfma_f32_32x32x16_bf16(ak1, qf[0], zf, 0, 0, 0);
#pragma unroll
    for (int c = 1; c < 4; ++c) {
      ak0 = *(const s8v*)&k_s[h][l31][c * 16 + hi * 8];
      ak1 = *(const s8v*)&k_s[h][32 + l31][c * 16 + hi * 8];
      s0 = __builtin_amdgcn_mfma_f32_32x32x16_bf16(ak0, qf[c], s0, 0, 0, 0);
      s1 = __builtin_amdgcn_mfma_f32_32x32x16_bf16(ak1, qf[c], s1, 0, 0, 0);
    }
    __builtin_amdgcn_s_setprio(0);

    // p = 2^score; mask as AND on packed bf16 pairs; rebuild PV A-frags
    s8v pf[4];
#pragma unroll
    for (int ni = 0; ni < 2; ++ni) {
      float p[16];
#pragma unroll
      for (int i2 = 0; i2 < 16; ++i2)
        p[i2] = __builtin_amdgcn_exp2f(ni ? s1[i2] : s0[i2]);
#pragma unroll
      for (int kcl = 0; kcl < 2; ++kcl) {
        const int rb = 8 * kcl;
        const uint4 mw = ni ? (kcl ? mwD : mwC) : (kcl ? mwB : mwA);
        unsigned x0 = pkbf(p[rb + 0], p[rb + 1]) & mw.x;
        unsigned x1 = pkbf(p[rb + 2], p[rb + 3]) & mw.y;
        unsigned y0 = pkbf(p[rb + 4], p[rb + 5]) & mw.z;
        unsigned y1 = pkbf(p[rb + 6], p[rb + 7]) & mw.w;
        asm("v_permlane32_swap_b32 %0, %1" : "+v"(x0), "+v"(y0));
        asm("v_permlane32_swap_b32 %0, %1" : "+v"(x1), "+v"(y1));
        union { uint4 u; s8v v; } cv;
        cv.u = make_uint4(x0, x1, y0, y1);
        pf[ni * 2 + kcl] = cv.v;
      }
    }

    // l += P @ ones; O += P @ V
    __builtin_amdgcn_s_setprio(1);
#pragma unroll
    for (int kc = 0; kc < 4; ++kc)
      lac = __builtin_amdgcn_mfma_f32_32x32x16_bf16(pf[kc], ones, lac, 0, 0, 0);
#pragma unroll
    for (int kc = 0; kc < 4; ++kc) {
      s8v bv0 = *(const s8v*)&v_s[h][l31][kc * 16 + hi * 8];
      s8v bv1 = *(const s8v*)&v_s[h][32 + l31][kc * 16 + hi * 8];
      o0 = __builtin_amdgcn_mfma_f32_32x32x16_bf16(pf[kc], bv0, o0, 0, 0, 0);
      o1 = __builtin_amdgcn_mfma_f32_32x32x16_bf16(pf[kc], bv1, o1, 0, 0, 0);
    }
    __builtin_amdgcn_s_setprio(0);

    __syncthreads();            // all reads of tile i done
    if (i < 15) WRITET();       // stage tile i+1 (regs loaded at iter i-1)
    if (i < 14) LOADT(i + 2);   // issue loads for tile i+2
    __syncthreads();            // tile i+1 visible
  }

  // combine key-halves: odd wave (h=1) -> LDS -> even wave adds + normalizes.
  // per qgroup a private region (k_s for g=0, v_s for g=1); stride 52 floats.
  float* cb = g ? (float*)&v_s[0][0][0] : (float*)&k_s[0][0][0];
  if (h == 1) {
#pragma unroll
    for (int r = 0; r < 16; r += 4) {
      *(float4*)&cb[lane * 52 + r]      = make_float4(o0[r], o0[r+1], o0[r+2], o0[r+3]);
      *(float4*)&cb[lane * 52 + 16 + r] = make_float4(o1[r], o1[r+1], o1[r+2], o1[r+3]);
      *(float4*)&cb[lane * 52 + 32 + r] = make_float4(lac[r], lac[r+1], lac[r+2], lac[r+3]);
    }
  }
  __syncthreads();
  if (h == 0) {
    const int b_ = bh >> 4, hh = bh & 15;
#pragma unroll
    for (int r = 0; r < 16; ++r) {
      const float oo0 = o0[r] + cb[lane * 52 + r];
      const float oo1 = o1[r] + cb[lane * 52 + 16 + r];
      const float ll  = lac[r] + cb[lane * 52 + 32 + r];
      const float inv = 1.f / ll;
      const int ql = (r & 3) + 8 * (r >> 2) + 4 * hi;
      const int srw = q0 + g * 32 + ql;
      const size_t base = ((size_t)b_ * 2048 + srw) * 1024 + hh * 64;
      ctx[base + l31] = f2bf(oo0 * inv);
      ctx[base + 32 + l31] = f2bf(oo1 * inv);
    }
  }
}

// ---------- output projection, 64x128 tile (R6 config) ----------
__global__ __launch_bounds__(256) void gemm_out_kernel(
    const unsigned short* __restrict__ A, const unsigned short* __restrict__ Wt,
    const float* __restrict__ bias, float* __restrict__ out) {
  __shared__ __align__(16) unsigned short As[64 * 32];
  __shared__ __align__(16) unsigned short Bs[128 * 32];

  const int tid = threadIdx.x;
  const int lane = tid & 63, w = tid >> 6, ln = lane & 15, quad = lane >> 4;
  const int wm = (w & 1) * 32, wn = (w >> 1) * 64;
  const int m0 = blockIdx.x * 64, n0 = blockIdx.y * 128;

  const int slr = lane >> 2;
  const int schunk = (lane & 3) ^ ((lane >> 3) & 3);
  const int cfrag = (quad ^ ((ln >> 1) & 3)) * 8;

  f4v zero = {0.f, 0.f, 0.f, 0.f};
  f4v acc[2][4];
  for (int mi = 0; mi < 2; ++mi)
    for (int ni = 0; ni < 4; ++ni) acc[mi][ni] = zero;

  for (int kt = 0; kt < 1024; kt += 32) {
    __syncthreads();
    gll16(&A[(size_t)(m0 + w * 16 + slr) * 1024 + kt + schunk * 8],        &As[(w * 16) * 32]);
    gll16(&Wt[(size_t)(n0 + w * 32 + slr) * 1024 + kt + schunk * 8],       &Bs[(w * 32) * 32]);
    gll16(&Wt[(size_t)(n0 + w * 32 + 16 + slr) * 1024 + kt + schunk * 8],  &Bs[(w * 32 + 16) * 32]);
    __syncthreads();
    s8v a[2], b[4];
    for (int mi = 0; mi < 2; ++mi) a[mi] = *(const s8v*)&As[(wm + mi * 16 + ln) * 32 + cfrag];
    for (int ni = 0; ni < 4; ++ni) b[ni] = *(const s8v*)&Bs[(wn + ni * 16 + ln) * 32 + cfrag];
    for (int mi = 0; mi < 2; ++mi)
      for (int ni = 0; ni < 4; ++ni)
        acc[mi][ni] = __builtin_amdgcn_mfma_f32_16x16x32_bf16(a[mi], b[ni], acc[mi][ni], 0, 0, 0);
  }

  for (int mi = 0; mi < 2; ++mi) {
    int rb = m0 + wm + mi * 16 + quad * 4;
    for (int ni = 0; ni < 4; ++ni) {
      int col = n0 + wn + ni * 16 + ln;
      float bvv = bias[col];
      for (int r = 0; r < 4; ++r)
        out[(size_t)(rb + r) * 1024 + col] = acc[mi][ni][r] + bvv;
    }
  }
}

extern "C" void kernel_launch(void* const* d_in, const int* in_sizes, int n_in,
                              void* d_out, int out_size, void* d_ws, size_t ws_size,
                              hipStream_t stream) {
  const float* Q  = (const float*)d_in[0];
  const float* K  = (const float*)d_in[1];
  const float* V  = (const float*)d_in[2];
  const int* mask = (const int*)d_in[3];
  const float* Wq = (const float*)d_in[4];
  const float* bq = (const float*)d_in[5];
  const float* Wk = (const float*)d_in[6];
  const float* bk = (const float*)d_in[7];
  const float* Wv = (const float*)d_in[8];
  const float* bv = (const float*)d_in[9];
  const float* Wo = (const float*)d_in[10];
  const float* bo = (const float*)d_in[11];
  float* out = (float*)d_out;

  char* ws = (char*)d_ws;
  const size_t MB = 1u << 20;
  unsigned short* qb  = (unsigned short*)(ws + 0 * MB);
  unsigned short* kb  = (unsigned short*)(ws + 8 * MB);
  unsigned short* vb  = (unsigned short*)(ws + 16 * MB);
  unsigned short* wqt = (unsigned short*)(ws + 24 * MB);
  unsigned short* wkt = (unsigned short*)(ws + 26 * MB);
  unsigned short* wvt = (unsigned short*)(ws + 28 * MB);
  unsigned short* wot = (unsigned short*)(ws + 30 * MB);
  unsigned short* qh  = (unsigned short*)(ws + 32 * MB);
  unsigned short* kh  = (unsigned short*)(ws + 40 * MB);
  unsigned short* vth = (unsigned short*)(ws + 48 * MB);
  unsigned* bmw       = (unsigned*)(ws + 56 * MB);       // 8 MB of packed mask words
  unsigned short* ctx = (unsigned short*)(ws + 16 * MB);  // aliases vb (dead after proj3)

  prep_kernel<<<21504, 256, 0, stream>>>(Q, K, V, qb, kb, vb,
                                         Wq, Wk, Wv, Wo, wqt, wkt, wvt, wot,
                                         mask, bmw);
  proj3_kernel<<<dim3(64, 8, 3), 256, 0, stream>>>(qb, kb, vb, wqt, wkt, wvt,
                                                   bq, bk, bv, qh, kh, vth);
  flash_kernel<<<dim3(32, 32), 256, 0, stream>>>(qh, kh, vth, bmw, ctx);
  gemm_out_kernel<<<dim3(64, 8), 256, 0, stream>>>(ctx, wot, bo, out);
}

// Round 4
// 246.129 us; speedup vs baseline: 1.0775x; 1.0775x over previous
//
#include <hip/hip_runtime.h>

// MHA: B=2, S=2048, D=1024, H=16, HD=64. fp32 in/out, bf16 MFMA internally.
// ws layout (64 MB): qb/kb/vb bf16 [4096,1024] @0/8/16MB; Wq/k/v/o^T bf16
// [1024,1024] @24/26/28/30MB; q(pre-scaled 0.125*log2e),k [B,H,S,HD] @32/40MB;
// v^T [B,H,HD,S] @48MB; bmw u32 mask-words [64][32][32][2][16] @56MB (8MB);
// ctx bf16 @16MB (aliases vb).
//
// R13: revert R12's key-split (doubled staging traffic, lockstep barriers ->
// 77us). Back to R11 structure (128 q-rows/block, 4 waves, dbuf K/V) + T15
// software pipeline: iter i issues S(i+1) MFMAs FIRST (K(i+1) already in LDS),
// then pack(i) VALU overlaps the matrix pipe, then PV(i). Fills the ~1900cyc
// serial-chain hole R11 had at 2 waves/SIMD. Two S states (sA/sB), unroll x2.

using s8v = __attribute__((ext_vector_type(8))) short;   // 8 bf16 (4 VGPRs)
using f4v = __attribute__((ext_vector_type(4))) float;   // MFMA acc (16x16)
using f16v = __attribute__((ext_vector_type(16))) float; // MFMA acc (32x32)
typedef unsigned long long u64;

__device__ __forceinline__ unsigned short f2bf(float f) {
  union { float f; unsigned int u; } v; v.f = f;
  return (unsigned short)((v.u + 0x7fffu + ((v.u >> 16) & 1u)) >> 16);  // RNE
}

// pack two f32 -> two bf16 (truncation): lo | hi<<16
__device__ __forceinline__ unsigned pkbf(float lo, float hi2) {
  return __builtin_amdgcn_perm(__float_as_uint(hi2), __float_as_uint(lo), 0x07060302);
}

__device__ __forceinline__ void gll16(const void* g, void* l) {
  __builtin_amdgcn_global_load_lds(
      (const __attribute__((address_space(1))) unsigned int*)g,
      (__attribute__((address_space(3))) unsigned int*)l, 16, 0, 0);
}

// ---------- merged prep: f2b (QKV), wtrans (4 weights), packed mask words ----------
// mask words: for flash lane (l31,hi) at (rowblk,it): 16 u32, widx = ni*8+kcl*4+e,
// word = (mask[q][k0]?0xFFFF:0) | (mask[q][k0+1]?0xFFFF0000:0),
// k0 = 64*it + 32*ni + 16*kcl + 4*hi + (e>>1)*8 + (e&1)*2, q = rowblk*32+l31.
__global__ void prep_kernel(const float* __restrict__ Q, const float* __restrict__ K,
                            const float* __restrict__ V,
                            unsigned short* __restrict__ qb, unsigned short* __restrict__ kb,
                            unsigned short* __restrict__ vb,
                            const float* __restrict__ W0, const float* __restrict__ W1,
                            const float* __restrict__ W2, const float* __restrict__ W3,
                            unsigned short* __restrict__ T0, unsigned short* __restrict__ T1,
                            unsigned short* __restrict__ T2, unsigned short* __restrict__ T3,
                            const int* __restrict__ mask, unsigned* __restrict__ bmw) {
  __shared__ unsigned short t[64][72];
  const int bid = blockIdx.x, tid = threadIdx.x;
  if (bid < 12288) {
    int z = bid >> 12;
    int idx = (bid & 4095) * 256 + tid;
    const float* in = (z == 0) ? Q : (z == 1) ? K : V;
    unsigned short* out = (z == 0) ? qb : (z == 1) ? kb : vb;
    float4 v = ((const float4*)in)[idx];
    ushort4 o;
    o.x = f2bf(v.x); o.y = f2bf(v.y); o.z = f2bf(v.z); o.w = f2bf(v.w);
    ((ushort4*)out)[idx] = o;
  } else if (bid < 13312) {
    int b = bid - 12288;
    int z = b >> 8, rem = b & 255;
    int k0 = (rem >> 4) * 64, n0 = (rem & 15) * 64;
    const float* W = (z == 0) ? W0 : (z == 1) ? W1 : (z == 2) ? W2 : W3;
    unsigned short* Wt = (z == 0) ? T0 : (z == 1) ? T1 : (z == 2) ? T2 : T3;
    for (int p = 0; p < 4; ++p) {
      int idx = p * 256 + tid;
      int row = idx >> 4, c4 = idx & 15;
      float4 v = *(const float4*)&W[(size_t)(k0 + row) * 1024 + n0 + c4 * 4];
      t[row][c4 * 4 + 0] = f2bf(v.x);
      t[row][c4 * 4 + 1] = f2bf(v.y);
      t[row][c4 * 4 + 2] = f2bf(v.z);
      t[row][c4 * 4 + 3] = f2bf(v.w);
    }
    __syncthreads();
    for (int p = 0; p < 2; ++p) {
      int idx = p * 256 + tid;
      int j = idx >> 3, c8 = idx & 7;
      unsigned short tmp[8];
      for (int i = 0; i < 8; ++i) tmp[i] = t[c8 * 8 + i][j];
      uint4 o;
      o.x = tmp[0] | ((unsigned)tmp[1] << 16);
      o.y = tmp[2] | ((unsigned)tmp[3] << 16);
      o.z = tmp[4] | ((unsigned)tmp[5] << 16);
      o.w = tmp[6] | ((unsigned)tmp[7] << 16);
      *(uint4*)&Wt[(size_t)(n0 + j) * 1024 + k0 + c8 * 8] = o;
    }
  } else {
    int g = (bid - 13312) * 256 + tid;          // [0, 2^21)
    int widx = g & 15, hi = (g >> 4) & 1, l31 = (g >> 5) & 31;
    int it = (g >> 10) & 31, rowblk = g >> 15;
    int ni = widx >> 3, kcl = (widx >> 2) & 1, e = widx & 3;
    int kk = 64 * it + 32 * ni + 16 * kcl + 4 * hi + (e >> 1) * 8 + (e & 1) * 2;
    int qrow = rowblk * 32 + l31;
    const int* mrow = mask + (size_t)qrow * 2048 + kk;
    unsigned wd = (mrow[0] ? 0xFFFFu : 0u) | (mrow[1] ? 0xFFFF0000u : 0u);
    bmw[g] = wd;
  }
}

// ---------- fused QKV projection GEMM, 64x128 tile (R6 config) ----------
// z=0: q*(0.125*log2e) -> [B,H,S,HD]; z=1: k -> [B,H,S,HD]; z=2: v -> v^T [B,H,HD,S]
__global__ __launch_bounds__(256) void proj3_kernel(
    const unsigned short* __restrict__ A0, const unsigned short* __restrict__ A1,
    const unsigned short* __restrict__ A2,
    const unsigned short* __restrict__ W0, const unsigned short* __restrict__ W1,
    const unsigned short* __restrict__ W2,
    const float* __restrict__ b0, const float* __restrict__ b1, const float* __restrict__ b2,
    unsigned short* __restrict__ oq, unsigned short* __restrict__ ok,
    unsigned short* __restrict__ ovt) {
  const int z = blockIdx.z;
  const unsigned short* A  = (z == 0) ? A0 : (z == 1) ? A1 : A2;
  const unsigned short* Wt = (z == 0) ? W0 : (z == 1) ? W1 : W2;
  const float* bias        = (z == 0) ? b0 : (z == 1) ? b1 : b2;

  __shared__ __align__(16) unsigned short As[64 * 32];
  __shared__ __align__(16) unsigned short Bs[128 * 32];

  const int tid = threadIdx.x;
  const int lane = tid & 63, w = tid >> 6, ln = lane & 15, quad = lane >> 4;
  const int wm = (w & 1) * 32, wn = (w >> 1) * 64;
  const int m0 = blockIdx.x * 64, n0 = blockIdx.y * 128;

  const int slr = lane >> 2;
  const int schunk = (lane & 3) ^ ((lane >> 3) & 3);
  const int cfrag = (quad ^ ((ln >> 1) & 3)) * 8;

  f4v zero = {0.f, 0.f, 0.f, 0.f};
  f4v acc[2][4];
  for (int mi = 0; mi < 2; ++mi)
    for (int ni = 0; ni < 4; ++ni) acc[mi][ni] = zero;

  for (int kt = 0; kt < 1024; kt += 32) {
    __syncthreads();
    gll16(&A[(size_t)(m0 + w * 16 + slr) * 1024 + kt + schunk * 8],        &As[(w * 16) * 32]);
    gll16(&Wt[(size_t)(n0 + w * 32 + slr) * 1024 + kt + schunk * 8],       &Bs[(w * 32) * 32]);
    gll16(&Wt[(size_t)(n0 + w * 32 + 16 + slr) * 1024 + kt + schunk * 8],  &Bs[(w * 32 + 16) * 32]);
    __syncthreads();
    s8v a[2], b[4];
    for (int mi = 0; mi < 2; ++mi) a[mi] = *(const s8v*)&As[(wm + mi * 16 + ln) * 32 + cfrag];
    for (int ni = 0; ni < 4; ++ni) b[ni] = *(const s8v*)&Bs[(wn + ni * 16 + ln) * 32 + cfrag];
    if (z < 2) {
      for (int mi = 0; mi < 2; ++mi)
        for (int ni = 0; ni < 4; ++ni)
          acc[mi][ni] = __builtin_amdgcn_mfma_f32_16x16x32_bf16(a[mi], b[ni], acc[mi][ni], 0, 0, 0);
    } else {
      for (int mi = 0; mi < 2; ++mi)
        for (int ni = 0; ni < 4; ++ni)
          acc[mi][ni] = __builtin_amdgcn_mfma_f32_16x16x32_bf16(b[ni], a[mi], acc[mi][ni], 0, 0, 0);
    }
  }

  if (z < 2) {
    const float qscale = (z == 0) ? 0.18033688f : 1.0f;  // 0.125 * log2(e)
    unsigned short* outp = (z == 0) ? oq : ok;
    for (int mi = 0; mi < 2; ++mi) {
      int rb = m0 + wm + mi * 16 + quad * 4;
      int b_ = rb >> 11;
      for (int ni = 0; ni < 4; ++ni) {
        int col = n0 + wn + ni * 16 + ln;
        float bvv = bias[col];
        int h = col >> 6, hd = col & 63;
        size_t ob = (size_t)(b_ * 16 + h) * 2048;
        for (int r = 0; r < 4; ++r) {
          int s = (rb + r) & 2047;
          outp[(ob + s) * 64 + hd] = f2bf((acc[mi][ni][r] + bvv) * qscale);
        }
      }
    }
  } else {
    for (int ni = 0; ni < 4; ++ni) {
      for (int r = 0; r < 4; ++r) {
        int colw = n0 + wn + ni * 16 + quad * 4 + r;
        int h = colw >> 6, hd = colw & 63;
        float bvv = bias[colw];
        for (int mi = 0; mi < 2; ++mi) {
          int sg = m0 + wm + mi * 16 + ln;
          int b_ = sg >> 11, ss = sg & 2047;
          ovt[((size_t)(b_ * 16 + h) * 64 + hd) * 2048 + ss] = f2bf(acc[mi][ni][r] + bvv);
        }
      }
    }
  }
}

// ---------- flash attention R13: 256 thr, 4 waves x 32 q-rows, pipelined ----------
#define FLASH_ITER(i, SIN0, SIN1, SOUT0, SOUT1)                                 \
  {                                                                             \
    const int cur = (i) & 1;                                                    \
    uint4 nA, nB, nC, nD;                                                       \
    if ((i) < 31) {                                                             \
      const uint4* m4 = (const uint4*)(mwp + ((i) + 1) * 1024);                 \
      nA = m4[0]; nB = m4[1]; nC = m4[2]; nD = m4[3];                           \
    }                                                                           \
    /* S(i+1): issue first so the matrix pipe runs under pack(i)'s VALU */      \
    __builtin_amdgcn_s_setprio(1);                                              \
    if ((i) < 31) {                                                             \
      s8v ak0 = *(const s8v*)&k_s[cur ^ 1][l31][hi * 8];                        \
      s8v ak1 = *(const s8v*)&k_s[cur ^ 1][32 + l31][hi * 8];                   \
      SOUT0 = __builtin_amdgcn_mfma_f32_32x32x16_bf16(ak0, qf[0], zf, 0, 0, 0); \
      SOUT1 = __builtin_amdgcn_mfma_f32_32x32x16_bf16(ak1, qf[0], zf, 0, 0, 0); \
      _Pragma("unroll")                                                         \
      for (int c = 1; c < 4; ++c) {                                             \
        ak0 = *(const s8v*)&k_s[cur ^ 1][l31][c * 16 + hi * 8];                 \
        ak1 = *(const s8v*)&k_s[cur ^ 1][32 + l31][c * 16 + hi * 8];            \
        SOUT0 = __builtin_amdgcn_mfma_f32_32x32x16_bf16(ak0, qf[c], SOUT0, 0, 0, 0); \
        SOUT1 = __builtin_amdgcn_mfma_f32_32x32x16_bf16(ak1, qf[c], SOUT1, 0, 0, 0); \
      }                                                                         \
    }                                                                           \
    __builtin_amdgcn_s_setprio(0);                                              \
    /* pack(i): p = 2^s * maskbit, to bf16 pairs, permlane -> PV A-frags */     \
    s8v pf[4];                                                                  \
    _Pragma("unroll")                                                           \
    for (int ni = 0; ni < 2; ++ni) {                                            \
      const f16v sv = ni ? SIN1 : SIN0;                                         \
      _Pragma("unroll")                                                         \
      for (int kcl = 0; kcl < 2; ++kcl) {                                       \
        const int rb = 8 * kcl;                                                 \
        const uint4 mw = ni ? (kcl ? mwD : mwC) : (kcl ? mwB : mwA);            \
        unsigned x0 = pkbf(__builtin_amdgcn_exp2f(sv[rb + 0]),                  \
                           __builtin_amdgcn_exp2f(sv[rb + 1])) & mw.x;          \
        unsigned x1 = pkbf(__builtin_amdgcn_exp2f(sv[rb + 2]),                  \
                           __builtin_amdgcn_exp2f(sv[rb + 3])) & mw.y;          \
        unsigned y0 = pkbf(__builtin_amdgcn_exp2f(sv[rb + 4]),                  \
                           __builtin_amdgcn_exp2f(sv[rb + 5])) & mw.z;          \
        unsigned y1 = pkbf(__builtin_amdgcn_exp2f(sv[rb + 6]),                  \
                           __builtin_amdgcn_exp2f(sv[rb + 7])) & mw.w;          \
        asm("v_permlane32_swap_b32 %0, %1" : "+v"(x0), "+v"(y0));               \
        asm("v_permlane32_swap_b32 %0, %1" : "+v"(x1), "+v"(y1));               \
        union { uint4 u; s8v v; } cv;                                           \
        cv.u = make_uint4(x0, x1, y0, y1);                                      \
        pf[ni * 2 + kcl] = cv.v;                                                \
      }                                                                         \
    }                                                                           \
    /* PV(i): l += P@ones, O += P@V */                                          \
    __builtin_amdgcn_s_setprio(1);                                              \
    _Pragma("unroll")                                                           \
    for (int kc = 0; kc < 4; ++kc)                                              \
      lac = __builtin_amdgcn_mfma_f32_32x32x16_bf16(pf[kc], ones, lac, 0, 0, 0);\
    _Pragma("unroll")                                                           \
    for (int kc = 0; kc < 4; ++kc) {                                            \
      s8v bv0 = *(const s8v*)&v_s[cur][l31][kc * 16 + hi * 8];                  \
      s8v bv1 = *(const s8v*)&v_s[cur][32 + l31][kc * 16 + hi * 8];             \
      o0 = __builtin_amdgcn_mfma_f32_32x32x16_bf16(pf[kc], bv0, o0, 0, 0, 0);   \
      o1 = __builtin_amdgcn_mfma_f32_32x32x16_bf16(pf[kc], bv1, o1, 0, 0, 0);   \
    }                                                                           \
    __builtin_amdgcn_s_setprio(0);                                              \
    __syncthreads();                     /* A: V(i)/K(i+1) reads done */        \
    if ((i) < 30) WRITET(cur);           /* tile i+2 -> buf cur */              \
    if ((i) < 29) LOADT((i) + 3);                                               \
    __syncthreads();                     /* B: tile i+2 visible for iter i+1 */ \
    mwA = nA; mwB = nB; mwC = nC; mwD = nD;                                     \
  }

__global__ __launch_bounds__(256, 2) void flash_kernel(
    const unsigned short* __restrict__ q, const unsigned short* __restrict__ k,
    const unsigned short* __restrict__ vt, const unsigned* __restrict__ bmw,
    unsigned short* __restrict__ ctx) {
  __shared__ __align__(16) unsigned short k_s[2][64][72];
  __shared__ __align__(16) unsigned short v_s[2][64][72];

  const int tid = threadIdx.x;
  const int lane = tid & 63, w = tid >> 6;
  const int l31 = lane & 31, hi = lane >> 5;
  const int q0 = blockIdx.x * 128;
  const int bh = blockIdx.y;
  const unsigned short* qg  = q  + ((size_t)bh * 2048 + q0) * 64;
  const unsigned short* kgb = k  + (size_t)bh * 2048 * 64;
  const unsigned short* vgb = vt + (size_t)bh * 64 * 2048;
  // mask-word base for this lane: bmw[rowblk][it][l31][hi][16]
  const unsigned* mwp = bmw + (size_t)(blockIdx.x * 4 + w) * 32768 + l31 * 32 + hi * 16;

  // Q fragments direct from global: wave w owns q-rows [w*32, w*32+32)
  const int qrow = w * 32 + l31;
  s8v qf[4];
#pragma unroll
  for (int c = 0; c < 4; ++c)
    qf[c] = *(const s8v*)&qg[(size_t)qrow * 64 + c * 16 + hi * 8];

  s8v ones;
#pragma unroll
  for (int i = 0; i < 8; ++i) ones[i] = (short)0x3F80;
  f16v zf;
#pragma unroll
  for (int i = 0; i < 16; ++i) zf[i] = 0.f;

  // staging: 256 threads x 4 uint4 (one K tile + one V tile)
  const int srow = tid >> 3, sc8 = tid & 7;  // rows srow and srow+32

  uint4 kr0, kr1, vr0, vr1;
  auto LOADT = [&](int it) {
    const int kk = it * 64;
    kr0 = *(const uint4*)&kgb[(size_t)(kk + srow) * 64 + sc8 * 8];
    kr1 = *(const uint4*)&kgb[(size_t)(kk + srow + 32) * 64 + sc8 * 8];
    vr0 = *(const uint4*)&vgb[(size_t)srow * 2048 + kk + sc8 * 8];
    vr1 = *(const uint4*)&vgb[(size_t)(srow + 32) * 2048 + kk + sc8 * 8];
  };
  auto WRITET = [&](int b) {
    *(uint4*)&k_s[b][srow][sc8 * 8] = kr0;
    *(uint4*)&k_s[b][srow + 32][sc8 * 8] = kr1;
    *(uint4*)&v_s[b][srow][sc8 * 8] = vr0;
    *(uint4*)&v_s[b][srow + 32][sc8 * 8] = vr1;
  };

  LOADT(0); WRITET(0);
  LOADT(1); WRITET(1);
  LOADT(2);
  __syncthreads();

  // mask words for tile 0
  uint4 mwA, mwB, mwC, mwD;
  {
    const uint4* m4 = (const uint4*)mwp;
    mwA = m4[0]; mwB = m4[1]; mwC = m4[2]; mwD = m4[3];
  }

  // S(0) from k_s[0]
  f16v sA0, sA1, sB0, sB1;
  {
    s8v ak0 = *(const s8v*)&k_s[0][l31][hi * 8];
    s8v ak1 = *(const s8v*)&k_s[0][32 + l31][hi * 8];
    sA0 = __builtin_amdgcn_mfma_f32_32x32x16_bf16(ak0, qf[0], zf, 0, 0, 0);
    sA1 = __builtin_amdgcn_mfma_f32_32x32x16_bf16(ak1, qf[0], zf, 0, 0, 0);
#pragma unroll
    for (int c = 1; c < 4; ++c) {
      ak0 = *(const s8v*)&k_s[0][l31][c * 16 + hi * 8];
      ak1 = *(const s8v*)&k_s[0][32 + l31][c * 16 + hi * 8];
      sA0 = __builtin_amdgcn_mfma_f32_32x32x16_bf16(ak0, qf[c], sA0, 0, 0, 0);
      sA1 = __builtin_amdgcn_mfma_f32_32x32x16_bf16(ak1, qf[c], sA1, 0, 0, 0);
    }
  }

  f16v o0, o1, lac;
#pragma unroll
  for (int i = 0; i < 16; ++i) { o0[i] = 0.f; o1[i] = 0.f; lac[i] = 0.f; }

  for (int ii = 0; ii < 16; ++ii) {
    const int i0 = ii * 2;
    FLASH_ITER(i0,     sA0, sA1, sB0, sB1);
    FLASH_ITER(i0 + 1, sB0, sB1, sA0, sA1);
  }

  // O row r -> q_local=(r&3)+8*(r>>2)+4*hi, col=lane&31 (+32 for o1)
  const int b_ = bh >> 4, h = bh & 15;
#pragma unroll
  for (int r = 0; r < 16; ++r) {
    const int ql = (r & 3) + 8 * (r >> 2) + 4 * hi;
    const float inv = 1.f / lac[r];
    const int srw = q0 + w * 32 + ql;
    const size_t base = ((size_t)b_ * 2048 + srw) * 1024 + h * 64;
    ctx[base + l31] = f2bf(o0[r] * inv);
    ctx[base + 32 + l31] = f2bf(o1[r] * inv);
  }
}

// ---------- output projection, 64x128 tile (R6 config) ----------
__global__ __launch_bounds__(256) void gemm_out_kernel(
    const unsigned short* __restrict__ A, const unsigned short* __restrict__ Wt,
    const float* __restrict__ bias, float* __restrict__ out) {
  __shared__ __align__(16) unsigned short As[64 * 32];
  __shared__ __align__(16) unsigned short Bs[128 * 32];

  const int tid = threadIdx.x;
  const int lane = tid & 63, w = tid >> 6, ln = lane & 15, quad = lane >> 4;
  const int wm = (w & 1) * 32, wn = (w >> 1) * 64;
  const int m0 = blockIdx.x * 64, n0 = blockIdx.y * 128;

  const int slr = lane >> 2;
  const int schunk = (lane & 3) ^ ((lane >> 3) & 3);
  const int cfrag = (quad ^ ((ln >> 1) & 3)) * 8;

  f4v zero = {0.f, 0.f, 0.f, 0.f};
  f4v acc[2][4];
  for (int mi = 0; mi < 2; ++mi)
    for (int ni = 0; ni < 4; ++ni) acc[mi][ni] = zero;

  for (int kt = 0; kt < 1024; kt += 32) {
    __syncthreads();
    gll16(&A[(size_t)(m0 + w * 16 + slr) * 1024 + kt + schunk * 8],        &As[(w * 16) * 32]);
    gll16(&Wt[(size_t)(n0 + w * 32 + slr) * 1024 + kt + schunk * 8],       &Bs[(w * 32) * 32]);
    gll16(&Wt[(size_t)(n0 + w * 32 + 16 + slr) * 1024 + kt + schunk * 8],  &Bs[(w * 32 + 16) * 32]);
    __syncthreads();
    s8v a[2], b[4];
    for (int mi = 0; mi < 2; ++mi) a[mi] = *(const s8v*)&As[(wm + mi * 16 + ln) * 32 + cfrag];
    for (int ni = 0; ni < 4; ++ni) b[ni] = *(const s8v*)&Bs[(wn + ni * 16 + ln) * 32 + cfrag];
    for (int mi = 0; mi < 2; ++mi)
      for (int ni = 0; ni < 4; ++ni)
        acc[mi][ni] = __builtin_amdgcn_mfma_f32_16x16x32_bf16(a[mi], b[ni], acc[mi][ni], 0, 0, 0);
  }

  for (int mi = 0; mi < 2; ++mi) {
    int rb = m0 + wm + mi * 16 + quad * 4;
    for (int ni = 0; ni < 4; ++ni) {
      int col = n0 + wn + ni * 16 + ln;
      float bvv = bias[col];
      for (int r = 0; r < 4; ++r)
        out[(size_t)(rb + r) * 1024 + col] = acc[mi][ni][r] + bvv;
    }
  }
}

extern "C" void kernel_launch(void* const* d_in, const int* in_sizes, int n_in,
                              void* d_out, int out_size, void* d_ws, size_t ws_size,
                              hipStream_t stream) {
  const float* Q  = (const float*)d_in[0];
  const float* K  = (const float*)d_in[1];
  const float* V  = (const float*)d_in[2];
  const int* mask = (const int*)d_in[3];
  const float* Wq = (const float*)d_in[4];
  const float* bq = (const float*)d_in[5];
  const float* Wk = (const float*)d_in[6];
  const float* bk = (const float*)d_in[7];
  const float* Wv = (const float*)d_in[8];
  const float* bv = (const float*)d_in[9];
  const float* Wo = (const float*)d_in[10];
  const float* bo = (const float*)d_in[11];
  float* out = (float*)d_out;

  char* ws = (char*)d_ws;
  const size_t MB = 1u << 20;
  unsigned short* qb  = (unsigned short*)(ws + 0 * MB);
  unsigned short* kb  = (unsigned short*)(ws + 8 * MB);
  unsigned short* vb  = (unsigned short*)(ws + 16 * MB);
  unsigned short* wqt = (unsigned short*)(ws + 24 * MB);
  unsigned short* wkt = (unsigned short*)(ws + 26 * MB);
  unsigned short* wvt = (unsigned short*)(ws + 28 * MB);
  unsigned short* wot = (unsigned short*)(ws + 30 * MB);
  unsigned short* qh  = (unsigned short*)(ws + 32 * MB);
  unsigned short* kh  = (unsigned short*)(ws + 40 * MB);
  unsigned short* vth = (unsigned short*)(ws + 48 * MB);
  unsigned* bmw       = (unsigned*)(ws + 56 * MB);       // 8 MB of packed mask words
  unsigned short* ctx = (unsigned short*)(ws + 16 * MB);  // aliases vb (dead after proj3)

  prep_kernel<<<21504, 256, 0, stream>>>(Q, K, V, qb, kb, vb,
                                         Wq, Wk, Wv, Wo, wqt, wkt, wvt, wot,
                                         mask, bmw);
  proj3_kernel<<<dim3(64, 8, 3), 256, 0, stream>>>(qb, kb, vb, wqt, wkt, wvt,
                                                   bq, bk, bv, qh, kh, vth);
  flash_kernel<<<dim3(16, 32), 256, 0, stream>>>(qh, kh, vth, bmw, ctx);
  gemm_out_kernel<<<dim3(64, 8), 256, 0, stream>>>(ctx, wot, bo, out);
}

// Round 5
// 245.946 us; speedup vs baseline: 1.0783x; 1.0007x over previous
//
#include <hip/hip_runtime.h>

// MHA: B=2, S=2048, D=1024, H=16, HD=64. fp32 in/out, bf16 MFMA internally.
// ws layout (64 MB): qb/kb/vb bf16 [4096,1024] @0/8/16MB; Wq/k/v/o^T bf16
// [1024,1024] @24/26/28/30MB; q(pre-scaled 0.125*log2e),k [B,H,S,HD] @32/40MB;
// v^T [B,H,HD,S] @48MB; bmw u32 mask-words [64][32][32][2][16] @56MB (8MB);
// ctx bf16 @16MB (aliases vb).
//
// R14: R13 still lost ~37%/iter to sync: (a) 2 barriers/iter from the 2-buffer
// WAR hazard, (b) __syncthreads' vmcnt(0) drain right after LOADT issue exposed
// full load latency each iter. Triple-buffer K/V -> reads (bV, bK) and write
// (bW) are disjoint every iter -> ONE barrier/iter; WRITET/LOADT hoisted to
// just after the S-MFMA issue so the end-of-iter drain has ~2000cyc of
// pack+PV to cover load latency. Buffers rotate via 3 ints (plain LDS addr
// math); sA/sB stay statically indexed via the x2 unroll.

using s8v = __attribute__((ext_vector_type(8))) short;   // 8 bf16 (4 VGPRs)
using f4v = __attribute__((ext_vector_type(4))) float;   // MFMA acc (16x16)
using f16v = __attribute__((ext_vector_type(16))) float; // MFMA acc (32x32)
typedef unsigned long long u64;

__device__ __forceinline__ unsigned short f2bf(float f) {
  union { float f; unsigned int u; } v; v.f = f;
  return (unsigned short)((v.u + 0x7fffu + ((v.u >> 16) & 1u)) >> 16);  // RNE
}

// pack two f32 -> two bf16 (truncation): lo | hi<<16
__device__ __forceinline__ unsigned pkbf(float lo, float hi2) {
  return __builtin_amdgcn_perm(__float_as_uint(hi2), __float_as_uint(lo), 0x07060302);
}

__device__ __forceinline__ void gll16(const void* g, void* l) {
  __builtin_amdgcn_global_load_lds(
      (const __attribute__((address_space(1))) unsigned int*)g,
      (__attribute__((address_space(3))) unsigned int*)l, 16, 0, 0);
}

// ---------- merged prep: f2b (QKV), wtrans (4 weights), packed mask words ----------
// mask words: for flash lane (l31,hi) at (rowblk,it): 16 u32, widx = ni*8+kcl*4+e,
// word = (mask[q][k0]?0xFFFF:0) | (mask[q][k0+1]?0xFFFF0000:0),
// k0 = 64*it + 32*ni + 16*kcl + 4*hi + (e>>1)*8 + (e&1)*2, q = rowblk*32+l31.
__global__ void prep_kernel(const float* __restrict__ Q, const float* __restrict__ K,
                            const float* __restrict__ V,
                            unsigned short* __restrict__ qb, unsigned short* __restrict__ kb,
                            unsigned short* __restrict__ vb,
                            const float* __restrict__ W0, const float* __restrict__ W1,
                            const float* __restrict__ W2, const float* __restrict__ W3,
                            unsigned short* __restrict__ T0, unsigned short* __restrict__ T1,
                            unsigned short* __restrict__ T2, unsigned short* __restrict__ T3,
                            const int* __restrict__ mask, unsigned* __restrict__ bmw) {
  __shared__ unsigned short t[64][72];
  const int bid = blockIdx.x, tid = threadIdx.x;
  if (bid < 12288) {
    int z = bid >> 12;
    int idx = (bid & 4095) * 256 + tid;
    const float* in = (z == 0) ? Q : (z == 1) ? K : V;
    unsigned short* out = (z == 0) ? qb : (z == 1) ? kb : vb;
    float4 v = ((const float4*)in)[idx];
    ushort4 o;
    o.x = f2bf(v.x); o.y = f2bf(v.y); o.z = f2bf(v.z); o.w = f2bf(v.w);
    ((ushort4*)out)[idx] = o;
  } else if (bid < 13312) {
    int b = bid - 12288;
    int z = b >> 8, rem = b & 255;
    int k0 = (rem >> 4) * 64, n0 = (rem & 15) * 64;
    const float* W = (z == 0) ? W0 : (z == 1) ? W1 : (z == 2) ? W2 : W3;
    unsigned short* Wt = (z == 0) ? T0 : (z == 1) ? T1 : (z == 2) ? T2 : T3;
    for (int p = 0; p < 4; ++p) {
      int idx = p * 256 + tid;
      int row = idx >> 4, c4 = idx & 15;
      float4 v = *(const float4*)&W[(size_t)(k0 + row) * 1024 + n0 + c4 * 4];
      t[row][c4 * 4 + 0] = f2bf(v.x);
      t[row][c4 * 4 + 1] = f2bf(v.y);
      t[row][c4 * 4 + 2] = f2bf(v.z);
      t[row][c4 * 4 + 3] = f2bf(v.w);
    }
    __syncthreads();
    for (int p = 0; p < 2; ++p) {
      int idx = p * 256 + tid;
      int j = idx >> 3, c8 = idx & 7;
      unsigned short tmp[8];
      for (int i = 0; i < 8; ++i) tmp[i] = t[c8 * 8 + i][j];
      uint4 o;
      o.x = tmp[0] | ((unsigned)tmp[1] << 16);
      o.y = tmp[2] | ((unsigned)tmp[3] << 16);
      o.z = tmp[4] | ((unsigned)tmp[5] << 16);
      o.w = tmp[6] | ((unsigned)tmp[7] << 16);
      *(uint4*)&Wt[(size_t)(n0 + j) * 1024 + k0 + c8 * 8] = o;
    }
  } else {
    int g = (bid - 13312) * 256 + tid;          // [0, 2^21)
    int widx = g & 15, hi = (g >> 4) & 1, l31 = (g >> 5) & 31;
    int it = (g >> 10) & 31, rowblk = g >> 15;
    int ni = widx >> 3, kcl = (widx >> 2) & 1, e = widx & 3;
    int kk = 64 * it + 32 * ni + 16 * kcl + 4 * hi + (e >> 1) * 8 + (e & 1) * 2;
    int qrow = rowblk * 32 + l31;
    const int* mrow = mask + (size_t)qrow * 2048 + kk;
    unsigned wd = (mrow[0] ? 0xFFFFu : 0u) | (mrow[1] ? 0xFFFF0000u : 0u);
    bmw[g] = wd;
  }
}

// ---------- fused QKV projection GEMM, 64x128 tile (R6 config) ----------
// z=0: q*(0.125*log2e) -> [B,H,S,HD]; z=1: k -> [B,H,S,HD]; z=2: v -> v^T [B,H,HD,S]
__global__ __launch_bounds__(256) void proj3_kernel(
    const unsigned short* __restrict__ A0, const unsigned short* __restrict__ A1,
    const unsigned short* __restrict__ A2,
    const unsigned short* __restrict__ W0, const unsigned short* __restrict__ W1,
    const unsigned short* __restrict__ W2,
    const float* __restrict__ b0, const float* __restrict__ b1, const float* __restrict__ b2,
    unsigned short* __restrict__ oq, unsigned short* __restrict__ ok,
    unsigned short* __restrict__ ovt) {
  const int z = blockIdx.z;
  const unsigned short* A  = (z == 0) ? A0 : (z == 1) ? A1 : A2;
  const unsigned short* Wt = (z == 0) ? W0 : (z == 1) ? W1 : W2;
  const float* bias        = (z == 0) ? b0 : (z == 1) ? b1 : b2;

  __shared__ __align__(16) unsigned short As[64 * 32];
  __shared__ __align__(16) unsigned short Bs[128 * 32];

  const int tid = threadIdx.x;
  const int lane = tid & 63, w = tid >> 6, ln = lane & 15, quad = lane >> 4;
  const int wm = (w & 1) * 32, wn = (w >> 1) * 64;
  const int m0 = blockIdx.x * 64, n0 = blockIdx.y * 128;

  const int slr = lane >> 2;
  const int schunk = (lane & 3) ^ ((lane >> 3) & 3);
  const int cfrag = (quad ^ ((ln >> 1) & 3)) * 8;

  f4v zero = {0.f, 0.f, 0.f, 0.f};
  f4v acc[2][4];
  for (int mi = 0; mi < 2; ++mi)
    for (int ni = 0; ni < 4; ++ni) acc[mi][ni] = zero;

  for (int kt = 0; kt < 1024; kt += 32) {
    __syncthreads();
    gll16(&A[(size_t)(m0 + w * 16 + slr) * 1024 + kt + schunk * 8],        &As[(w * 16) * 32]);
    gll16(&Wt[(size_t)(n0 + w * 32 + slr) * 1024 + kt + schunk * 8],       &Bs[(w * 32) * 32]);
    gll16(&Wt[(size_t)(n0 + w * 32 + 16 + slr) * 1024 + kt + schunk * 8],  &Bs[(w * 32 + 16) * 32]);
    __syncthreads();
    s8v a[2], b[4];
    for (int mi = 0; mi < 2; ++mi) a[mi] = *(const s8v*)&As[(wm + mi * 16 + ln) * 32 + cfrag];
    for (int ni = 0; ni < 4; ++ni) b[ni] = *(const s8v*)&Bs[(wn + ni * 16 + ln) * 32 + cfrag];
    if (z < 2) {
      for (int mi = 0; mi < 2; ++mi)
        for (int ni = 0; ni < 4; ++ni)
          acc[mi][ni] = __builtin_amdgcn_mfma_f32_16x16x32_bf16(a[mi], b[ni], acc[mi][ni], 0, 0, 0);
    } else {
      for (int mi = 0; mi < 2; ++mi)
        for (int ni = 0; ni < 4; ++ni)
          acc[mi][ni] = __builtin_amdgcn_mfma_f32_16x16x32_bf16(b[ni], a[mi], acc[mi][ni], 0, 0, 0);
    }
  }

  if (z < 2) {
    const float qscale = (z == 0) ? 0.18033688f : 1.0f;  // 0.125 * log2(e)
    unsigned short* outp = (z == 0) ? oq : ok;
    for (int mi = 0; mi < 2; ++mi) {
      int rb = m0 + wm + mi * 16 + quad * 4;
      int b_ = rb >> 11;
      for (int ni = 0; ni < 4; ++ni) {
        int col = n0 + wn + ni * 16 + ln;
        float bvv = bias[col];
        int h = col >> 6, hd = col & 63;
        size_t ob = (size_t)(b_ * 16 + h) * 2048;
        for (int r = 0; r < 4; ++r) {
          int s = (rb + r) & 2047;
          outp[(ob + s) * 64 + hd] = f2bf((acc[mi][ni][r] + bvv) * qscale);
        }
      }
    }
  } else {
    for (int ni = 0; ni < 4; ++ni) {
      for (int r = 0; r < 4; ++r) {
        int colw = n0 + wn + ni * 16 + quad * 4 + r;
        int h = colw >> 6, hd = colw & 63;
        float bvv = bias[colw];
        for (int mi = 0; mi < 2; ++mi) {
          int sg = m0 + wm + mi * 16 + ln;
          int b_ = sg >> 11, ss = sg & 2047;
          ovt[((size_t)(b_ * 16 + h) * 64 + hd) * 2048 + ss] = f2bf(acc[mi][ni][r] + bvv);
        }
      }
    }
  }
}

// ---------- flash attention R14: 4 waves x 32 q-rows, 3-buf LDS, 1 barrier/iter ----------
#define FLASH_ITER(i, SIN0, SIN1, SOUT0, SOUT1)                                 \
  {                                                                             \
    uint4 nA, nB, nC, nD;                                                       \
    if ((i) < 31) {                                                             \
      const uint4* m4 = (const uint4*)(mwp + ((i) + 1) * 1024);                 \
      nA = m4[0]; nB = m4[1]; nC = m4[2]; nD = m4[3];                           \
    }                                                                           \
    /* S(i+1): issue first so the matrix pipe runs under pack(i)'s VALU */      \
    __builtin_amdgcn_s_setprio(1);                                              \
    if ((i) < 31) {                                                             \
      s8v ak0 = *(const s8v*)&k_s[bK][l31][hi * 8];                             \
      s8v ak1 = *(const s8v*)&k_s[bK][32 + l31][hi * 8];                        \
      SOUT0 = __builtin_amdgcn_mfma_f32_32x32x16_bf16(ak0, qf[0], zf, 0, 0, 0); \
      SOUT1 = __builtin_amdgcn_mfma_f32_32x32x16_bf16(ak1, qf[0], zf, 0, 0, 0); \
      _Pragma("unroll")                                                         \
      for (int c = 1; c < 4; ++c) {                                             \
        ak0 = *(const s8v*)&k_s[bK][l31][c * 16 + hi * 8];                      \
        ak1 = *(const s8v*)&k_s[bK][32 + l31][c * 16 + hi * 8];                 \
        SOUT0 = __builtin_amdgcn_mfma_f32_32x32x16_bf16(ak0, qf[c], SOUT0, 0, 0, 0); \
        SOUT1 = __builtin_amdgcn_mfma_f32_32x32x16_bf16(ak1, qf[c], SOUT1, 0, 0, 0); \
      }                                                                         \
    }                                                                           \
    __builtin_amdgcn_s_setprio(0);                                              \
    /* stage early: ds_writes + next loads get pack+PV (~2000cyc) of cover */   \
    if ((i) < 30) WRITET(bW);            /* tile i+2 -> buf bW */               \
    if ((i) < 29) LOADT((i) + 3);                                               \
    /* pack(i): p = 2^s * maskbit, to bf16 pairs, permlane -> PV A-frags */     \
    s8v pf[4];                                                                  \
    _Pragma("unroll")                                                           \
    for (int ni = 0; ni < 2; ++ni) {                                            \
      const f16v sv = ni ? SIN1 : SIN0;                                         \
      _Pragma("unroll")                                                         \
      for (int kcl = 0; kcl < 2; ++kcl) {                                       \
        const int rb = 8 * kcl;                                                 \
        const uint4 mw = ni ? (kcl ? mwD : mwC) : (kcl ? mwB : mwA);            \
        unsigned x0 = pkbf(__builtin_amdgcn_exp2f(sv[rb + 0]),                  \
                           __builtin_amdgcn_exp2f(sv[rb + 1])) & mw.x;          \
        unsigned x1 = pkbf(__builtin_amdgcn_exp2f(sv[rb + 2]),                  \
                           __builtin_amdgcn_exp2f(sv[rb + 3])) & mw.y;          \
        unsigned y0 = pkbf(__builtin_amdgcn_exp2f(sv[rb + 4]),                  \
                           __builtin_amdgcn_exp2f(sv[rb + 5])) & mw.z;          \
        unsigned y1 = pkbf(__builtin_amdgcn_exp2f(sv[rb + 6]),                  \
                           __builtin_amdgcn_exp2f(sv[rb + 7])) & mw.w;          \
        asm("v_permlane32_swap_b32 %0, %1" : "+v"(x0), "+v"(y0));               \
        asm("v_permlane32_swap_b32 %0, %1" : "+v"(x1), "+v"(y1));               \
        union { uint4 u; s8v v; } cv;                                           \
        cv.u = make_uint4(x0, x1, y0, y1);                                      \
        pf[ni * 2 + kcl] = cv.v;                                                \
      }                                                                         \
    }                                                                           \
    /* PV(i): l += P@ones, O += P@V */                                          \
    __builtin_amdgcn_s_setprio(1);                                              \
    _Pragma("unroll")                                                           \
    for (int kc = 0; kc < 4; ++kc)                                              \
      lac = __builtin_amdgcn_mfma_f32_32x32x16_bf16(pf[kc], ones, lac, 0, 0, 0);\
    _Pragma("unroll")                                                           \
    for (int kc = 0; kc < 4; ++kc) {                                            \
      s8v bv0 = *(const s8v*)&v_s[bV][l31][kc * 16 + hi * 8];                   \
      s8v bv1 = *(const s8v*)&v_s[bV][32 + l31][kc * 16 + hi * 8];              \
      o0 = __builtin_amdgcn_mfma_f32_32x32x16_bf16(pf[kc], bv0, o0, 0, 0, 0);   \
      o1 = __builtin_amdgcn_mfma_f32_32x32x16_bf16(pf[kc], bv1, o1, 0, 0, 0);   \
    }                                                                           \
    __builtin_amdgcn_s_setprio(0);                                              \
    __syncthreads();   /* writes of tile i+2 sealed; reads of bV/bK done */     \
    { int t_ = bV; bV = bK; bK = bW; bW = t_; }                                 \
    mwA = nA; mwB = nB; mwC = nC; mwD = nD;                                     \
  }

__global__ __launch_bounds__(256, 2) void flash_kernel(
    const unsigned short* __restrict__ q, const unsigned short* __restrict__ k,
    const unsigned short* __restrict__ vt, const unsigned* __restrict__ bmw,
    unsigned short* __restrict__ ctx) {
  __shared__ __align__(16) unsigned short k_s[3][64][72];
  __shared__ __align__(16) unsigned short v_s[3][64][72];

  const int tid = threadIdx.x;
  const int lane = tid & 63, w = tid >> 6;
  const int l31 = lane & 31, hi = lane >> 5;
  const int q0 = blockIdx.x * 128;
  const int bh = blockIdx.y;
  const unsigned short* qg  = q  + ((size_t)bh * 2048 + q0) * 64;
  const unsigned short* kgb = k  + (size_t)bh * 2048 * 64;
  const unsigned short* vgb = vt + (size_t)bh * 64 * 2048;
  // mask-word base for this lane: bmw[rowblk][it][l31][hi][16]
  const unsigned* mwp = bmw + (size_t)(blockIdx.x * 4 + w) * 32768 + l31 * 32 + hi * 16;

  // Q fragments direct from global: wave w owns q-rows [w*32, w*32+32)
  const int qrow = w * 32 + l31;
  s8v qf[4];
#pragma unroll
  for (int c = 0; c < 4; ++c)
    qf[c] = *(const s8v*)&qg[(size_t)qrow * 64 + c * 16 + hi * 8];

  s8v ones;
#pragma unroll
  for (int i = 0; i < 8; ++i) ones[i] = (short)0x3F80;
  f16v zf;
#pragma unroll
  for (int i = 0; i < 16; ++i) zf[i] = 0.f;

  // staging: 256 threads x 4 uint4 (one K tile + one V tile)
  const int srow = tid >> 3, sc8 = tid & 7;  // rows srow and srow+32

  uint4 kr0, kr1, vr0, vr1;
  auto LOADT = [&](int it) {
    const int kk = it * 64;
    kr0 = *(const uint4*)&kgb[(size_t)(kk + srow) * 64 + sc8 * 8];
    kr1 = *(const uint4*)&kgb[(size_t)(kk + srow + 32) * 64 + sc8 * 8];
    vr0 = *(const uint4*)&vgb[(size_t)srow * 2048 + kk + sc8 * 8];
    vr1 = *(const uint4*)&vgb[(size_t)(srow + 32) * 2048 + kk + sc8 * 8];
  };
  auto WRITET = [&](int b) {
    *(uint4*)&k_s[b][srow][sc8 * 8] = kr0;
    *(uint4*)&k_s[b][srow + 32][sc8 * 8] = kr1;
    *(uint4*)&v_s[b][srow][sc8 * 8] = vr0;
    *(uint4*)&v_s[b][srow + 32][sc8 * 8] = vr1;
  };

  LOADT(0); WRITET(0);
  LOADT(1); WRITET(1);
  LOADT(2);
  __syncthreads();

  // mask words for tile 0
  uint4 mwA, mwB, mwC, mwD;
  {
    const uint4* m4 = (const uint4*)mwp;
    mwA = m4[0]; mwB = m4[1]; mwC = m4[2]; mwD = m4[3];
  }

  // S(0) from k_s[0]
  f16v sA0, sA1, sB0, sB1;
  {
    s8v ak0 = *(const s8v*)&k_s[0][l31][hi * 8];
    s8v ak1 = *(const s8v*)&k_s[0][32 + l31][hi * 8];
    sA0 = __builtin_amdgcn_mfma_f32_32x32x16_bf16(ak0, qf[0], zf, 0, 0, 0);
    sA1 = __builtin_amdgcn_mfma_f32_32x32x16_bf16(ak1, qf[0], zf, 0, 0, 0);
#pragma unroll
    for (int c = 1; c < 4; ++c) {
      ak0 = *(const s8v*)&k_s[0][l31][c * 16 + hi * 8];
      ak1 = *(const s8v*)&k_s[0][32 + l31][c * 16 + hi * 8];
      sA0 = __builtin_amdgcn_mfma_f32_32x32x16_bf16(ak0, qf[c], sA0, 0, 0, 0);
      sA1 = __builtin_amdgcn_mfma_f32_32x32x16_bf16(ak1, qf[c], sA1, 0, 0, 0);
    }
  }

  f16v o0, o1, lac;
#pragma unroll
  for (int i = 0; i < 16; ++i) { o0[i] = 0.f; o1[i] = 0.f; lac[i] = 0.f; }

  int bV = 0, bK = 1, bW = 2;
  for (int ii = 0; ii < 16; ++ii) {
    const int i0 = ii * 2;
    FLASH_ITER(i0,     sA0, sA1, sB0, sB1);
    FLASH_ITER(i0 + 1, sB0, sB1, sA0, sA1);
  }

  // O row r -> q_local=(r&3)+8*(r>>2)+4*hi, col=lane&31 (+32 for o1)
  const int b_ = bh >> 4, h = bh & 15;
#pragma unroll
  for (int r = 0; r < 16; ++r) {
    const int ql = (r & 3) + 8 * (r >> 2) + 4 * hi;
    const float inv = 1.f / lac[r];
    const int srw = q0 + w * 32 + ql;
    const size_t base = ((size_t)b_ * 2048 + srw) * 1024 + h * 64;
    ctx[base + l31] = f2bf(o0[r] * inv);
    ctx[base + 32 + l31] = f2bf(o1[r] * inv);
  }
}

// ---------- output projection, 64x128 tile (R6 config) ----------
__global__ __launch_bounds__(256) void gemm_out_kernel(
    const unsigned short* __restrict__ A, const unsigned short* __restrict__ Wt,
    const float* __restrict__ bias, float* __restrict__ out) {
  __shared__ __align__(16) unsigned short As[64 * 32];
  __shared__ __align__(16) unsigned short Bs[128 * 32];

  const int tid = threadIdx.x;
  const int lane = tid & 63, w = tid >> 6, ln = lane & 15, quad = lane >> 4;
  const int wm = (w & 1) * 32, wn = (w >> 1) * 64;
  const int m0 = blockIdx.x * 64, n0 = blockIdx.y * 128;

  const int slr = lane >> 2;
  const int schunk = (lane & 3) ^ ((lane >> 3) & 3);
  const int cfrag = (quad ^ ((ln >> 1) & 3)) * 8;

  f4v zero = {0.f, 0.f, 0.f, 0.f};
  f4v acc[2][4];
  for (int mi = 0; mi < 2; ++mi)
    for (int ni = 0; ni < 4; ++ni) acc[mi][ni] = zero;

  for (int kt = 0; kt < 1024; kt += 32) {
    __syncthreads();
    gll16(&A[(size_t)(m0 + w * 16 + slr) * 1024 + kt + schunk * 8],        &As[(w * 16) * 32]);
    gll16(&Wt[(size_t)(n0 + w * 32 + slr) * 1024 + kt + schunk * 8],       &Bs[(w * 32) * 32]);
    gll16(&Wt[(size_t)(n0 + w * 32 + 16 + slr) * 1024 + kt + schunk * 8],  &Bs[(w * 32 + 16) * 32]);
    __syncthreads();
    s8v a[2], b[4];
    for (int mi = 0; mi < 2; ++mi) a[mi] = *(const s8v*)&As[(wm + mi * 16 + ln) * 32 + cfrag];
    for (int ni = 0; ni < 4; ++ni) b[ni] = *(const s8v*)&Bs[(wn + ni * 16 + ln) * 32 + cfrag];
    for (int mi = 0; mi < 2; ++mi)
      for (int ni = 0; ni < 4; ++ni)
        acc[mi][ni] = __builtin_amdgcn_mfma_f32_16x16x32_bf16(a[mi], b[ni], acc[mi][ni], 0, 0, 0);
  }

  for (int mi = 0; mi < 2; ++mi) {
    int rb = m0 + wm + mi * 16 + quad * 4;
    for (int ni = 0; ni < 4; ++ni) {
      int col = n0 + wn + ni * 16 + ln;
      float bvv = bias[col];
      for (int r = 0; r < 4; ++r)
        out[(size_t)(rb + r) * 1024 + col] = acc[mi][ni][r] + bvv;
    }
  }
}

extern "C" void kernel_launch(void* const* d_in, const int* in_sizes, int n_in,
                              void* d_out, int out_size, void* d_ws, size_t ws_size,
                              hipStream_t stream) {
  const float* Q  = (const float*)d_in[0];
  const float* K  = (const float*)d_in[1];
  const float* V  = (const float*)d_in[2];
  const int* mask = (const int*)d_in[3];
  const float* Wq = (const float*)d_in[4];
  const float* bq = (const float*)d_in[5];
  const float* Wk = (const float*)d_in[6];
  const float* bk = (const float*)d_in[7];
  const float* Wv = (const float*)d_in[8];
  const float* bv = (const float*)d_in[9];
  const float* Wo = (const float*)d_in[10];
  const float* bo = (const float*)d_in[11];
  float* out = (float*)d_out;

  char* ws = (char*)d_ws;
  const size_t MB = 1u << 20;
  unsigned short* qb  = (unsigned short*)(ws + 0 * MB);
  unsigned short* kb  = (unsigned short*)(ws + 8 * MB);
  unsigned short* vb  = (unsigned short*)(ws + 16 * MB);
  unsigned short* wqt = (unsigned short*)(ws + 24 * MB);
  unsigned short* wkt = (unsigned short*)(ws + 26 * MB);
  unsigned short* wvt = (unsigned short*)(ws + 28 * MB);
  unsigned short* wot = (unsigned short*)(ws + 30 * MB);
  unsigned short* qh  = (unsigned short*)(ws + 32 * MB);
  unsigned short* kh  = (unsigned short*)(ws + 40 * MB);
  unsigned short* vth = (unsigned short*)(ws + 48 * MB);
  unsigned* bmw       = (unsigned*)(ws + 56 * MB);       // 8 MB of packed mask words
  unsigned short* ctx = (unsigned short*)(ws + 16 * MB);  // aliases vb (dead after proj3)

  prep_kernel<<<21504, 256, 0, stream>>>(Q, K, V, qb, kb, vb,
                                         Wq, Wk, Wv, Wo, wqt, wkt, wvt, wot,
                                         mask, bmw);
  proj3_kernel<<<dim3(64, 8, 3), 256, 0, stream>>>(qb, kb, vb, wqt, wkt, wvt,
                                                   bq, bk, bv, qh, kh, vth);
  flash_kernel<<<dim3(16, 32), 256, 0, stream>>>(qh, kh, vth, bmw, ctx);
  gemm_out_kernel<<<dim3(64, 8), 256, 0, stream>>>(ctx, wot, bo, out);
}